// Round 7
// baseline (576.117 us; speedup 1.0000x reference)
//
#include <hip/hip_runtime.h>
#include <hip/hip_fp16.h>
#include <hip/hip_cooperative_groups.h>

namespace cg = cooperative_groups;

#define NNODES 50000
#define NEDGES 800000
#define NEG_SLOPE 0.2f
#define NTOT (NEDGES + NNODES)
#define NSCANB ((NNODES + 255) / 256)   // 196 blocks carry the node-scan

typedef _Float16 half8 __attribute__((ext_vector_type(8)));
typedef float f32x4 __attribute__((ext_vector_type(4)));

// ---------------- cooperative prep ----------------
// phases: deg=0 -> [hist | W2T | layer1_proj] -> scanA -> scanB -> scanC+cursor -> scatter
__global__ void prep_coop(const int* __restrict__ srcs, const int* __restrict__ dsts,
                          int* __restrict__ deg, int* __restrict__ rowstart,
                          int* __restrict__ partials, int* __restrict__ blockoff,
                          int* __restrict__ cursor, int* __restrict__ srclist,
                          const float* __restrict__ W2, _Float16* __restrict__ W2T,
                          const float* __restrict__ x, const float* __restrict__ W1,
                          const float* __restrict__ att_src, const float* __restrict__ att_dst,
                          __half* __restrict__ h1, float* __restrict__ asrc4,
                          float* __restrict__ adst4) {
    cg::grid_group grid = cg::this_grid();
    const int b = blockIdx.x, t = threadIdx.x;
    const int tid = b * 256 + t;
    const int nthr = gridDim.x * 256;
    __shared__ int wsum[4];

    // phase 0: zero degree counters (d_ws is poisoned before every launch)
    for (int i = tid; i < NNODES; i += nthr) deg[i] = 0;
    grid.sync();

    // phase 1a: histogram of real edges
    for (int e = tid; e < NEDGES; e += nthr) atomicAdd(&deg[dsts[e]], 1);
    // phase 1b: W2 [256][64] f32 -> W2T [64][256] f16
    for (int i = tid; i < 64 * 256; i += nthr) {
        int n = i >> 8, k = i & 255;
        W2T[n * 256 + k] = (_Float16)W2[k * 64 + n];
    }
    // phase 1c: layer1 projection, one wave per node (loops)
    {
        int wid = t >> 6, c = t & 63;
        int wglob = b * 4 + wid, wtot = gridDim.x * 4;
        for (int nid = wglob; nid < NNODES; nid += wtot) {
            float a0 = 0.f, a1 = 0.f, a2 = 0.f, a3 = 0.f;
#pragma unroll
            for (int k = 0; k < 15; ++k) {
                float xk = x[nid * 15 + k];                       // uniform -> s_load
                float4 wv = *(const float4*)(W1 + k * 256 + c * 4);
                a0 += xk * wv.x; a1 += xk * wv.y; a2 += xk * wv.z; a3 += xk * wv.w;
            }
            __half2 r0 = __floats2half2_rn(a0, a1), r1 = __floats2half2_rn(a2, a3);
            float2 st; *(__half2*)&st.x = r0; *(__half2*)&st.y = r1;
            *(float2*)(h1 + (size_t)nid * 256 + c * 4) = st;
            float4 as = *(const float4*)(att_src + c * 4);
            float4 av = *(const float4*)(att_dst + c * 4);
            float ps = a0 * as.x + a1 * as.y + a2 * as.z + a3 * as.w;
            float pd = a0 * av.x + a1 * av.y + a2 * av.z + a3 * av.w;
#pragma unroll
            for (int off = 1; off < 16; off <<= 1) {
                ps += __shfl_xor(ps, off, 64);
                pd += __shfl_xor(pd, off, 64);
            }
            if ((c & 15) == 0) {
                asrc4[nid * 4 + (c >> 4)] = ps;
                adst4[nid * 4 + (c >> 4)] = pd;
            }
        }
    }
    grid.sync();

    // phase 2: scanA — per-block exclusive scan of (deg+1)
    if (b < NSCANB) {
        int lane = t & 63, wid = t >> 6;
        int i = b * 256 + t;
        int v = (i < NNODES) ? deg[i] + 1 : 0;   // +1 = self-loop
        int incl = v;
#pragma unroll
        for (int off = 1; off < 64; off <<= 1) {
            int u = __shfl_up(incl, off, 64);
            if (lane >= off) incl += u;
        }
        if (lane == 63) wsum[wid] = incl;
        __syncthreads();
        int w0 = wsum[0], w1 = wsum[1], w2 = wsum[2], w3 = wsum[3];
        int woff = (wid > 0 ? w0 : 0) + (wid > 1 ? w1 : 0) + (wid > 2 ? w2 : 0);
        if (i < NNODES) rowstart[i] = woff + (incl - v);
        if (t == 0) partials[b] = w0 + w1 + w2 + w3;
    }
    grid.sync();

    // phase 3: scanB — block 0 scans the 196 block totals
    if (b == 0) {
        int lane = t & 63, wid = t >> 6;
        int v = (t < NSCANB) ? partials[t] : 0;
        int incl = v;
#pragma unroll
        for (int off = 1; off < 64; off <<= 1) {
            int u = __shfl_up(incl, off, 64);
            if (lane >= off) incl += u;
        }
        if (lane == 63) wsum[wid] = incl;
        __syncthreads();
        int w0 = wsum[0], w1 = wsum[1], w2 = wsum[2];
        int woff = (wid > 0 ? w0 : 0) + (wid > 1 ? w1 : 0) + (wid > 2 ? w2 : 0);
        if (t < NSCANB) blockoff[t] = woff + (incl - v);
        if (t == 0) rowstart[NNODES] = NTOT;
    }
    grid.sync();

    // phase 4: scanC — add block offsets, init cursor
    if (b < NSCANB) {
        int i = b * 256 + t;
        if (i < NNODES) {
            int v = rowstart[i] + blockoff[b];
            rowstart[i] = v;
            cursor[i] = v;
        }
    }
    grid.sync();

    // phase 5: scatter (absolute positions via cursor)
    for (int e = tid; e < NTOT; e += nthr) {
        if (e < NEDGES) {
            int s = srcs[e], d = dsts[e];
            srclist[atomicAdd(&cursor[d], 1)] = s;
        } else {
            int d = e - NEDGES;
            srclist[atomicAdd(&cursor[d], 1)] = d;  // self-loop
        }
    }
}

// ---------------- layer 1 aggregation ----------------
// one wave per node; 2 half-waves x 4 edges per iteration = 8 gathers in flight.
// packed-fp16 accumulation (__hfma2), z in f32; one xor-32 reduce at the end.
__global__ void layer1_aggr(const __half* __restrict__ h1, const int* __restrict__ rowstart,
                            const int* __restrict__ srclist,
                            const float* __restrict__ asrc4, const float* __restrict__ adst4,
                            const float* __restrict__ b1, __half* __restrict__ out1) {
    int wid = threadIdx.x >> 6, lane = threadIdx.x & 63;
    int nid = blockIdx.x * 4 + wid;
    int hf = lane >> 5, l32 = lane & 31;
    int h = l32 >> 3;                       // head (8 lanes x 8 dims per head)
    int beg = __builtin_amdgcn_readfirstlane(rowstart[nid]);
    int end = __builtin_amdgcn_readfirstlane(rowstart[nid + 1]);
    float ad = adst4[nid * 4 + h];
    const __half* hb = h1 + l32 * 8;        // lane's dim-octet base
    __half2 z16 = __float2half2_rn(0.f);
    __half2 acc0 = z16, acc1 = z16, acc2 = z16, acc3 = z16;
    float zs = 0.f;
    for (int i0 = beg; i0 < end; i0 += 8) {
#pragma unroll
        for (int u = 0; u < 4; ++u) {
            int i = i0 + hf + 2 * u;
            bool valid = i < end;
            int s = valid ? srclist[i] : 0;
            half8 g = *(const half8*)(hb + (size_t)s * 256);   // 256 B per half-wave
            float e = asrc4[s * 4 + h] + ad;
            e = fmaxf(e, NEG_SLOPE * e);
            float w = valid ? __expf(e) : 0.f;                 // unnormalized softmax
            zs += w;
            __half2 wh = __float2half2_rn(w);
            const __half2* gp = (const __half2*)&g;
            acc0 = __hfma2(wh, gp[0], acc0);
            acc1 = __hfma2(wh, gp[1], acc1);
            acc2 = __hfma2(wh, gp[2], acc2);
            acc3 = __hfma2(wh, gp[3], acc3);
        }
    }
    float2 f0 = __half22float2(acc0), f1 = __half22float2(acc1);
    float2 f2 = __half22float2(acc2), f3 = __half22float2(acc3);
    float a0 = f0.x, a1 = f0.y, a2 = f1.x, a3 = f1.y;
    float a4 = f2.x, a5 = f2.y, a6 = f3.x, a7 = f3.y;
    a0 += __shfl_xor(a0, 32, 64); a1 += __shfl_xor(a1, 32, 64);
    a2 += __shfl_xor(a2, 32, 64); a3 += __shfl_xor(a3, 32, 64);
    a4 += __shfl_xor(a4, 32, 64); a5 += __shfl_xor(a5, 32, 64);
    a6 += __shfl_xor(a6, 32, 64); a7 += __shfl_xor(a7, 32, 64);
    zs += __shfl_xor(zs, 32, 64);
    if (hf == 0) {
        float rz = 1.f / zs;
        float4 bl = *(const float4*)(b1 + l32 * 8);
        float4 bh = *(const float4*)(b1 + l32 * 8 + 4);
        float o0 = a0*rz+bl.x, o1 = a1*rz+bl.y, o2 = a2*rz+bl.z, o3 = a3*rz+bl.w;
        float o4 = a4*rz+bh.x, o5 = a5*rz+bh.y, o6 = a6*rz+bh.z, o7 = a7*rz+bh.w;
        o0 = o0 > 0.f ? o0 : __expf(o0) - 1.f;  // ELU
        o1 = o1 > 0.f ? o1 : __expf(o1) - 1.f;
        o2 = o2 > 0.f ? o2 : __expf(o2) - 1.f;
        o3 = o3 > 0.f ? o3 : __expf(o3) - 1.f;
        o4 = o4 > 0.f ? o4 : __expf(o4) - 1.f;
        o5 = o5 > 0.f ? o5 : __expf(o5) - 1.f;
        o6 = o6 > 0.f ? o6 : __expf(o6) - 1.f;
        o7 = o7 > 0.f ? o7 : __expf(o7) - 1.f;
        half8 st;
        st[0]=(_Float16)o0; st[1]=(_Float16)o1; st[2]=(_Float16)o2; st[3]=(_Float16)o3;
        st[4]=(_Float16)o4; st[5]=(_Float16)o5; st[6]=(_Float16)o6; st[7]=(_Float16)o7;
        *(half8*)((_Float16*)out1 + (size_t)nid * 256 + l32 * 8) = st;
    }
}

// ---------------- layer 2 ----------------

// MFMA GEMM: h2[50000x64] = out1[50000x256] @ W2 (f16 in, f32 acc, f16 out),
// with fused attention dots (heads=1) in the epilogue.
__global__ __launch_bounds__(256) void layer2_gemm(const __half* __restrict__ out1,
                                                   const _Float16* __restrict__ W2T,
                                                   __half* __restrict__ h2,
                                                   const float* __restrict__ att_src2,
                                                   const float* __restrict__ att_dst2,
                                                   float* __restrict__ as2,
                                                   float* __restrict__ ad2) {
    int w = threadIdx.x >> 6, lane = threadIdx.x & 63;
    int m16 = lane & 15, quad = lane >> 4;
    int r0 = blockIdx.x * 64 + w * 16;
    const _Float16* A = (const _Float16*)out1;
    f32x4 acc[4] = {{0.f,0.f,0.f,0.f},{0.f,0.f,0.f,0.f},{0.f,0.f,0.f,0.f},{0.f,0.f,0.f,0.f}};
    int row = r0 + m16; if (row >= NNODES) row = NNODES - 1;   // clamp tail reads
#pragma unroll
    for (int k0 = 0; k0 < 256; k0 += 32) {
        half8 a = *(const half8*)(A + (size_t)row * 256 + k0 + quad * 8);
#pragma unroll
        for (int nt = 0; nt < 4; ++nt) {
            half8 b = *(const half8*)(W2T + (size_t)(nt * 16 + m16) * 256 + k0 + quad * 8);
            acc[nt] = __builtin_amdgcn_mfma_f32_16x16x32_f16(a, b, acc[nt], 0, 0, 0);
        }
    }
    __shared__ _Float16 tile[64][72];
#pragma unroll
    for (int nt = 0; nt < 4; ++nt)
#pragma unroll
        for (int r = 0; r < 4; ++r)
            tile[w * 16 + quad * 4 + r][nt * 16 + m16] = (_Float16)acc[nt][r];
    __syncthreads();
    int t = threadIdx.x;
    int trow = t >> 2, seg = t & 3;
    int rg = blockIdx.x * 64 + trow;
    if (rg < NNODES) {
        float4 v0 = *(float4*)&tile[trow][seg * 16];
        float4 v1 = *(float4*)&tile[trow][seg * 16 + 8];
        _Float16* dst = (_Float16*)h2 + (size_t)rg * 64 + seg * 16;
        *(float4*)dst = v0;
        *(float4*)(dst + 8) = v1;
        const _Float16* hv = &tile[trow][seg * 16];
        float ps = 0.f, pd = 0.f;
#pragma unroll
        for (int j = 0; j < 16; ++j) {
            float v = (float)hv[j];
            ps += v * att_src2[seg * 16 + j];
            pd += v * att_dst2[seg * 16 + j];
        }
        ps += __shfl_xor(ps, 1, 64); ps += __shfl_xor(ps, 2, 64);
        pd += __shfl_xor(pd, 1, 64); pd += __shfl_xor(pd, 2, 64);
        if (seg == 0) { as2[rg] = ps; ad2[rg] = pd; }
    }
}

// one wave per node; 4 groups of 16 lanes x 4 edges per iteration = 16 gathers in flight.
__global__ void layer2_aggr(const __half* __restrict__ h2, const int* __restrict__ rowstart,
                            const int* __restrict__ srclist,
                            const float* __restrict__ as2, const float* __restrict__ ad2,
                            const float* __restrict__ b2, float* __restrict__ out2) {
    int wid = threadIdx.x >> 6, lane = threadIdx.x & 63;
    int nid = blockIdx.x * 4 + wid;
    int q = lane >> 4, c = lane & 15;
    int beg = __builtin_amdgcn_readfirstlane(rowstart[nid]);
    int end = __builtin_amdgcn_readfirstlane(rowstart[nid + 1]);
    float ad = ad2[nid];
    const __half* hb = h2 + c * 4;
    __half2 z16 = __float2half2_rn(0.f);
    __half2 acc0 = z16, acc1 = z16;
    float zs = 0.f;
    for (int i0 = beg; i0 < end; i0 += 16) {
#pragma unroll
        for (int u = 0; u < 4; ++u) {
            int i = i0 + q + 4 * u;
            bool valid = i < end;
            int s = valid ? srclist[i] : 0;
            float2 gv = *(const float2*)(hb + (size_t)s * 64);   // 8 B = 4 dims
            float e = as2[s] + ad;
            e = fmaxf(e, NEG_SLOPE * e);
            float w = valid ? __expf(e) : 0.f;
            zs += w;
            __half2 wh = __float2half2_rn(w);
            acc0 = __hfma2(wh, *(__half2*)&gv.x, acc0);
            acc1 = __hfma2(wh, *(__half2*)&gv.y, acc1);
        }
    }
    float2 f0 = __half22float2(acc0), f1 = __half22float2(acc1);
    float ax = f0.x, ay = f0.y, az = f1.x, aw = f1.y;
#pragma unroll
    for (int off = 16; off < 64; off <<= 1) {
        ax += __shfl_xor(ax, off, 64);
        ay += __shfl_xor(ay, off, 64);
        az += __shfl_xor(az, off, 64);
        aw += __shfl_xor(aw, off, 64);
        zs += __shfl_xor(zs, off, 64);
    }
    if (lane < 16) {
        float rz = 1.f / zs;
        float4 bo = ((const float4*)b2)[c];
        float4 st = make_float4(ax * rz + bo.x, ay * rz + bo.y,
                                az * rz + bo.z, aw * rz + bo.w);
        *(float4*)(out2 + (size_t)nid * 64 + c * 4) = st;
    }
}

// ---------------- final mean over nodes ----------------

__global__ void reduce_kernel(const float* __restrict__ out2, float* __restrict__ dout) {
    int t = threadIdx.x;
    int col = t & 63, sub = t >> 6;
    float acc = 0.f;
    for (int r = blockIdx.x * 4 + sub; r < NNODES; r += 256 * 4)
        acc += out2[r * 64 + col];
    __shared__ float sh[256];
    sh[t] = acc;
    __syncthreads();
    if (t < 64) {
        float v = sh[t] + sh[t + 64] + sh[t + 128] + sh[t + 192];
        atomicAdd(&dout[t], v * (1.0f / NNODES));
    }
}

// ---------------- launch ----------------

extern "C" void kernel_launch(void* const* d_in, const int* in_sizes, int n_in,
                              void* d_out, int out_size, void* d_ws, size_t ws_size,
                              hipStream_t stream) {
    const float* x        = (const float*)d_in[0];
    const int*   ei       = (const int*)d_in[1];   // [2, E] -> src row then dst row
    const float* W1       = (const float*)d_in[2];
    const float* att_src1 = (const float*)d_in[3];
    const float* att_dst1 = (const float*)d_in[4];
    const float* b1       = (const float*)d_in[5];
    const float* W2       = (const float*)d_in[6];
    const float* att_src2 = (const float*)d_in[7];
    const float* att_dst2 = (const float*)d_in[8];
    const float* b2       = (const float*)d_in[9];
    float* out = (float*)d_out;

    char* ws = (char*)d_ws;
    size_t off = 0;
    auto take = [&](size_t bytes) -> char* {
        char* p = ws + off;
        off = (off + bytes + 255) & ~(size_t)255;
        return p;
    };
    int*      deg      = (int*)take(NNODES * sizeof(int));
    int*      rowstart = (int*)take((NNODES + 1) * sizeof(int));
    int*      cursor   = (int*)take(NNODES * sizeof(int));
    int*      partials = (int*)take(256 * sizeof(int));
    int*      blockoff = (int*)take(256 * sizeof(int));
    int*      srclist  = (int*)take(((size_t)NTOT + 16) * sizeof(int));
    float*    asrc4    = (float*)take((size_t)NNODES * 4 * sizeof(float));
    float*    adst4    = (float*)take((size_t)NNODES * 4 * sizeof(float));
    __half*   h1       = (__half*)take((size_t)NNODES * 256 * sizeof(__half));
    __half*   out1     = (__half*)take((size_t)NNODES * 256 * sizeof(__half));
    _Float16* W2T      = (_Float16*)take(64 * 256 * sizeof(_Float16));
    __half*   h2       = (__half*)take((size_t)NNODES * 64 * sizeof(__half));
    float*    as2      = (float*)take((size_t)NNODES * sizeof(float));
    float*    ad2      = (float*)take((size_t)NNODES * sizeof(float));
    float*    out2     = (float*)take((size_t)NNODES * 64 * sizeof(float));

    const int* srcs = ei;
    const int* dsts = ei + NEDGES;

    hipMemsetAsync(d_out, 0, 64 * sizeof(float), stream);

    void* args[] = {
        (void*)&srcs, (void*)&dsts, (void*)&deg, (void*)&rowstart,
        (void*)&partials, (void*)&blockoff, (void*)&cursor, (void*)&srclist,
        (void*)&W2, (void*)&W2T, (void*)&x, (void*)&W1,
        (void*)&att_src1, (void*)&att_dst1, (void*)&h1, (void*)&asrc4, (void*)&adst4
    };
    hipLaunchCooperativeKernel((void*)prep_coop, dim3(512), dim3(256), args, 0, stream);

    layer1_aggr<<<NNODES / 4, 256, 0, stream>>>(h1, rowstart, srclist, asrc4, adst4, b1, out1);

    layer2_gemm<<<(NNODES + 63) / 64, 256, 0, stream>>>(out1, W2T, h2, att_src2, att_dst2,
                                                        as2, ad2);
    layer2_aggr<<<NNODES / 4, 256, 0, stream>>>(h2, rowstart, srclist, as2, ad2, b2, out2);

    reduce_kernel<<<256, 256, 0, stream>>>(out2, out);
}

// Round 8
// 285.520 us; speedup vs baseline: 2.0178x; 2.0178x over previous
//
#include <hip/hip_runtime.h>
#include <hip/hip_fp16.h>

#define NNODES 50000
#define NEDGES 800000
#define NEG_SLOPE 0.2f
#define NTOT (NEDGES + NNODES)
#define NB_NODE ((NNODES + 255) / 256)   // 196

typedef _Float16 half8 __attribute__((ext_vector_type(8)));
typedef _Float16 half4 __attribute__((ext_vector_type(4)));
typedef float f32x4 __attribute__((ext_vector_type(4)));

// ---------------- setup: deg=1, W2T, x16 (padded fp32), folded att dots ----------------
// wa[k][h] = sum_d W1[k][h*64+d]*att_src[h][d]  (15x4, computed per block in LDS)
// asrc4[n][h] = x[n][:15] . wa[:][h]   (exact: h1 never materialized)
__global__ void setup_kernel(const float* __restrict__ x, const float* __restrict__ W1,
                             const float* __restrict__ att_src, const float* __restrict__ att_dst,
                             const float* __restrict__ W2,
                             int* __restrict__ deg, float* __restrict__ x16,
                             float* __restrict__ asrc4, float* __restrict__ adst4,
                             _Float16* __restrict__ W2T) {
    int b = blockIdx.x, t = threadIdx.x;
    __shared__ float swa[16][4], swd[16][4];
    if (t < 128) {
        int k = (t & 63) >> 2, h = t & 3;
        float s = 0.f;
        if (k < 15) {
            const float* att = (t < 64) ? att_src : att_dst;
#pragma unroll 16
            for (int d = 0; d < 64; ++d)
                s += W1[k * 256 + h * 64 + d] * att[h * 64 + d];
        }
        if (t < 64) swa[k][h] = s; else swd[k][h] = s;
    }
    // W2 [256][64] f32 -> W2T [64][256] f16 (blocks 0..63)
    int tid = b * 256 + t;
    if (tid < 64 * 256) {
        int n = tid >> 8, k = tid & 255;
        W2T[n * 256 + k] = (_Float16)W2[k * 64 + n];
    }
    __syncthreads();
    int nid = tid;
    if (nid < NNODES) {
        deg[nid] = 1;                                   // self-loop
        float xv[16];
#pragma unroll
        for (int k = 0; k < 15; ++k) xv[k] = x[nid * 15 + k];
        xv[15] = 0.f;
#pragma unroll
        for (int k = 0; k < 16; k += 4)
            *(float4*)(x16 + (size_t)nid * 16 + k) = make_float4(xv[k], xv[k+1], xv[k+2], xv[k+3]);
        float ps[4] = {0.f, 0.f, 0.f, 0.f}, pd[4] = {0.f, 0.f, 0.f, 0.f};
#pragma unroll
        for (int k = 0; k < 15; ++k)
#pragma unroll
            for (int h = 0; h < 4; ++h) {
                ps[h] += xv[k] * swa[k][h];
                pd[h] += xv[k] * swd[k][h];
            }
        *(float4*)(asrc4 + nid * 4) = make_float4(ps[0], ps[1], ps[2], ps[3]);
        *(float4*)(adst4 + nid * 4) = make_float4(pd[0], pd[1], pd[2], pd[3]);
    }
}

// ---------------- graph prep (discrete; R6-proven) ----------------

__global__ void hist_kernel(const int* __restrict__ dsts, int* __restrict__ deg) {
    int e = blockIdx.x * blockDim.x + threadIdx.x;
    if (e < NEDGES) atomicAdd(&deg[dsts[e]], 1);
}

__global__ void scanA(const int* __restrict__ deg, int* __restrict__ rowstart,
                      int* __restrict__ partials) {
    int b = blockIdx.x, t = threadIdx.x, lane = t & 63, wid = t >> 6;
    int i = b * 256 + t;
    int v = (i < NNODES) ? deg[i] : 0;
    int incl = v;
#pragma unroll
    for (int off = 1; off < 64; off <<= 1) {
        int u = __shfl_up(incl, off, 64);
        if (lane >= off) incl += u;
    }
    __shared__ int ws[4];
    if (lane == 63) ws[wid] = incl;
    __syncthreads();
    int w0 = ws[0], w1 = ws[1], w2 = ws[2], w3 = ws[3];
    int woff = (wid > 0 ? w0 : 0) + (wid > 1 ? w1 : 0) + (wid > 2 ? w2 : 0);
    if (i < NNODES) rowstart[i] = woff + (incl - v);
    if (t == 0) partials[b] = w0 + w1 + w2 + w3;
}

__global__ void scanB(const int* __restrict__ partials, int* __restrict__ blockoff,
                      int* __restrict__ rowstart, int nb) {
    int t = threadIdx.x, lane = t & 63, wid = t >> 6;
    int v = (t < nb) ? partials[t] : 0;
    int incl = v;
#pragma unroll
    for (int off = 1; off < 64; off <<= 1) {
        int u = __shfl_up(incl, off, 64);
        if (lane >= off) incl += u;
    }
    __shared__ int ws[4];
    if (lane == 63) ws[wid] = incl;
    __syncthreads();
    int w0 = ws[0], w1 = ws[1], w2 = ws[2];
    int woff = (wid > 0 ? w0 : 0) + (wid > 1 ? w1 : 0) + (wid > 2 ? w2 : 0);
    if (t < nb) blockoff[t] = woff + (incl - v);
    if (t == 0) rowstart[NNODES] = NTOT;
}

__global__ void scanC(int* __restrict__ rowstart, const int* __restrict__ blockoff,
                      int* __restrict__ cursor) {
    int b = blockIdx.x, t = threadIdx.x;
    int i = b * 256 + t;
    if (i < NNODES) {
        int v = rowstart[i] + blockoff[b];
        rowstart[i] = v;
        cursor[i] = v;
    }
}

__global__ void scatter_kernel(const int* __restrict__ srcs, const int* __restrict__ dsts,
                               int* __restrict__ cursor, int* __restrict__ srclist) {
    int e = blockIdx.x * blockDim.x + threadIdx.x;
    if (e < NEDGES) {
        int s = srcs[e], d = dsts[e];
        srclist[atomicAdd(&cursor[d], 1)] = s;
    } else if (e < NTOT) {
        int d = e - NEDGES;
        srclist[atomicAdd(&cursor[d], 1)] = d;  // self-loop
    }
}

// ---------------- layer 1: fused aggregate + projection ----------------
// Linearity: sum_e w_e*h1[src_e] = (sum_e w_e*x[src_e]) @ W1.
// One wave per node. lane = h*16+k owns acc[h][k]; gathers are L2-resident
// (x16 = 3.2 MB, asrc4 = 0.8 MB per XCD). z redundant per lane -> no reduction.
// Epilogue: normalize, LDS broadcast, project through W1, bias+ELU, fp16 store.
__global__ void layer1_aggr(const float* __restrict__ x16, const int* __restrict__ rowstart,
                            const int* __restrict__ srclist,
                            const float* __restrict__ asrc4, const float* __restrict__ adst4,
                            const float* __restrict__ W1, const float* __restrict__ b1,
                            __half* __restrict__ out1) {
    int wid = threadIdx.x >> 6, lane = threadIdx.x & 63;
    int nid = blockIdx.x * 4 + wid;
    int h = lane >> 4, k = lane & 15;
    int beg = __builtin_amdgcn_readfirstlane(rowstart[nid]);
    int end = __builtin_amdgcn_readfirstlane(rowstart[nid + 1]);
    float ad = adst4[nid * 4 + h];
    float acc = 0.f, zs = 0.f;
    int nfull = beg + ((end - beg) & ~1);
    for (int i0 = beg; i0 < nfull; i0 += 2) {          // 2 independent L2-hit gathers
        int s0 = srclist[i0];                          // uniform -> s_load
        int s1 = srclist[i0 + 1];
        float xv0 = x16[s0 * 16 + k];                  // one 64 B line per edge
        float xv1 = x16[s1 * 16 + k];
        float e0 = asrc4[s0 * 4 + h] + ad;
        float e1 = asrc4[s1 * 4 + h] + ad;
        e0 = fmaxf(e0, NEG_SLOPE * e0);
        e1 = fmaxf(e1, NEG_SLOPE * e1);
        float w0 = __expf(e0), w1 = __expf(e1);        // unnormalized softmax (exact for w/z)
        zs += w0 + w1;
        acc = fmaf(w0, xv0, acc);
        acc = fmaf(w1, xv1, acc);
    }
    if (nfull < end) {
        int s = srclist[nfull];
        float xv = x16[s * 16 + k];
        float e = asrc4[s * 4 + h] + ad;
        e = fmaxf(e, NEG_SLOPE * e);
        float w = __expf(e);
        zs += w;
        acc = fmaf(w, xv, acc);
    }
    __shared__ float sacc[4][64];
    sacc[wid][lane] = acc * (1.f / zs);                // wave-coherent: no barrier needed
    int c = lane, h2 = c >> 4;                         // lane -> out dims c*4..c*4+3
    float o0 = 0.f, o1 = 0.f, o2 = 0.f, o3 = 0.f;
#pragma unroll
    for (int kk = 0; kk < 15; ++kk) {
        float a = sacc[wid][h2 * 16 + kk];             // broadcast within 16-lane group
        float4 wv = *(const float4*)(W1 + kk * 256 + c * 4);   // L1-resident (15 KB)
        o0 = fmaf(a, wv.x, o0); o1 = fmaf(a, wv.y, o1);
        o2 = fmaf(a, wv.z, o2); o3 = fmaf(a, wv.w, o3);
    }
    float4 bo = *(const float4*)(b1 + c * 4);
    o0 += bo.x; o1 += bo.y; o2 += bo.z; o3 += bo.w;
    o0 = o0 > 0.f ? o0 : __expf(o0) - 1.f;             // ELU
    o1 = o1 > 0.f ? o1 : __expf(o1) - 1.f;
    o2 = o2 > 0.f ? o2 : __expf(o2) - 1.f;
    o3 = o3 > 0.f ? o3 : __expf(o3) - 1.f;
    half4 st;
    st[0] = (_Float16)o0; st[1] = (_Float16)o1; st[2] = (_Float16)o2; st[3] = (_Float16)o3;
    *(half4*)((_Float16*)out1 + (size_t)nid * 256 + c * 4) = st;
}

// ---------------- layer 2 ----------------

// MFMA GEMM: h2[50000x64] = out1[50000x256] @ W2 (f16 in, f32 acc, f16 out),
// fused attention dots (heads=1) in the epilogue.
__global__ __launch_bounds__(256) void layer2_gemm(const __half* __restrict__ out1,
                                                   const _Float16* __restrict__ W2T,
                                                   __half* __restrict__ h2,
                                                   const float* __restrict__ att_src2,
                                                   const float* __restrict__ att_dst2,
                                                   float* __restrict__ as2,
                                                   float* __restrict__ ad2) {
    int w = threadIdx.x >> 6, lane = threadIdx.x & 63;
    int m16 = lane & 15, quad = lane >> 4;
    int r0 = blockIdx.x * 64 + w * 16;
    const _Float16* A = (const _Float16*)out1;
    f32x4 acc[4] = {{0.f,0.f,0.f,0.f},{0.f,0.f,0.f,0.f},{0.f,0.f,0.f,0.f},{0.f,0.f,0.f,0.f}};
    int row = r0 + m16; if (row >= NNODES) row = NNODES - 1;   // clamp tail reads
#pragma unroll
    for (int k0 = 0; k0 < 256; k0 += 32) {
        half8 a = *(const half8*)(A + (size_t)row * 256 + k0 + quad * 8);
#pragma unroll
        for (int nt = 0; nt < 4; ++nt) {
            half8 b = *(const half8*)(W2T + (size_t)(nt * 16 + m16) * 256 + k0 + quad * 8);
            acc[nt] = __builtin_amdgcn_mfma_f32_16x16x32_f16(a, b, acc[nt], 0, 0, 0);
        }
    }
    __shared__ _Float16 tile[64][72];
#pragma unroll
    for (int nt = 0; nt < 4; ++nt)
#pragma unroll
        for (int r = 0; r < 4; ++r)
            tile[w * 16 + quad * 4 + r][nt * 16 + m16] = (_Float16)acc[nt][r];
    __syncthreads();
    int t = threadIdx.x;
    int trow = t >> 2, seg = t & 3;
    int rg = blockIdx.x * 64 + trow;
    if (rg < NNODES) {
        float4 v0 = *(float4*)&tile[trow][seg * 16];
        float4 v1 = *(float4*)&tile[trow][seg * 16 + 8];
        _Float16* dst = (_Float16*)h2 + (size_t)rg * 64 + seg * 16;
        *(float4*)dst = v0;
        *(float4*)(dst + 8) = v1;
        const _Float16* hv = &tile[trow][seg * 16];
        float ps = 0.f, pd = 0.f;
#pragma unroll
        for (int j = 0; j < 16; ++j) {
            float v = (float)hv[j];
            ps += v * att_src2[seg * 16 + j];
            pd += v * att_dst2[seg * 16 + j];
        }
        ps += __shfl_xor(ps, 1, 64); ps += __shfl_xor(ps, 2, 64);
        pd += __shfl_xor(pd, 1, 64); pd += __shfl_xor(pd, 2, 64);
        if (seg == 0) { as2[rg] = ps; ad2[rg] = pd; }
    }
}

// one wave per node; 4 groups of 16 lanes x 4 edges per iteration = 16 gathers in flight.
__global__ void layer2_aggr(const __half* __restrict__ h2, const int* __restrict__ rowstart,
                            const int* __restrict__ srclist,
                            const float* __restrict__ as2, const float* __restrict__ ad2,
                            const float* __restrict__ b2, float* __restrict__ out2) {
    int wid = threadIdx.x >> 6, lane = threadIdx.x & 63;
    int nid = blockIdx.x * 4 + wid;
    int q = lane >> 4, c = lane & 15;
    int beg = __builtin_amdgcn_readfirstlane(rowstart[nid]);
    int end = __builtin_amdgcn_readfirstlane(rowstart[nid + 1]);
    float ad = ad2[nid];
    const __half* hb = h2 + c * 4;
    __half2 z16 = __float2half2_rn(0.f);
    __half2 acc0 = z16, acc1 = z16;
    float zs = 0.f;
    for (int i0 = beg; i0 < end; i0 += 16) {
#pragma unroll
        for (int u = 0; u < 4; ++u) {
            int i = i0 + q + 4 * u;
            bool valid = i < end;
            int s = valid ? srclist[i] : 0;
            float2 gv = *(const float2*)(hb + (size_t)s * 64);   // 8 B = 4 dims
            float e = as2[s] + ad;
            e = fmaxf(e, NEG_SLOPE * e);
            float w = valid ? __expf(e) : 0.f;
            zs += w;
            __half2 wh = __float2half2_rn(w);
            acc0 = __hfma2(wh, *(__half2*)&gv.x, acc0);
            acc1 = __hfma2(wh, *(__half2*)&gv.y, acc1);
        }
    }
    float2 f0 = __half22float2(acc0), f1 = __half22float2(acc1);
    float ax = f0.x, ay = f0.y, az = f1.x, aw = f1.y;
#pragma unroll
    for (int off = 16; off < 64; off <<= 1) {
        ax += __shfl_xor(ax, off, 64);
        ay += __shfl_xor(ay, off, 64);
        az += __shfl_xor(az, off, 64);
        aw += __shfl_xor(aw, off, 64);
        zs += __shfl_xor(zs, off, 64);
    }
    if (lane < 16) {
        float rz = 1.f / zs;
        float4 bo = ((const float4*)b2)[c];
        float4 st = make_float4(ax * rz + bo.x, ay * rz + bo.y,
                                az * rz + bo.z, aw * rz + bo.w);
        *(float4*)(out2 + (size_t)nid * 64 + c * 4) = st;
    }
}

// ---------------- final mean over nodes ----------------

__global__ void reduce_kernel(const float* __restrict__ out2, float* __restrict__ dout) {
    int t = threadIdx.x;
    int col = t & 63, sub = t >> 6;
    float acc = 0.f;
    for (int r = blockIdx.x * 4 + sub; r < NNODES; r += 256 * 4)
        acc += out2[r * 64 + col];
    __shared__ float sh[256];
    sh[t] = acc;
    __syncthreads();
    if (t < 64) {
        float v = sh[t] + sh[t + 64] + sh[t + 128] + sh[t + 192];
        atomicAdd(&dout[t], v * (1.0f / NNODES));
    }
}

// ---------------- launch ----------------

extern "C" void kernel_launch(void* const* d_in, const int* in_sizes, int n_in,
                              void* d_out, int out_size, void* d_ws, size_t ws_size,
                              hipStream_t stream) {
    const float* x        = (const float*)d_in[0];
    const int*   ei       = (const int*)d_in[1];   // [2, E] -> src row then dst row
    const float* W1       = (const float*)d_in[2];
    const float* att_src1 = (const float*)d_in[3];
    const float* att_dst1 = (const float*)d_in[4];
    const float* b1       = (const float*)d_in[5];
    const float* W2       = (const float*)d_in[6];
    const float* att_src2 = (const float*)d_in[7];
    const float* att_dst2 = (const float*)d_in[8];
    const float* b2       = (const float*)d_in[9];
    float* out = (float*)d_out;

    char* ws = (char*)d_ws;
    size_t off = 0;
    auto take = [&](size_t bytes) -> char* {
        char* p = ws + off;
        off = (off + bytes + 255) & ~(size_t)255;
        return p;
    };
    int*      deg      = (int*)take(NNODES * sizeof(int));
    int*      rowstart = (int*)take((NNODES + 1) * sizeof(int));
    int*      cursor   = (int*)take(NNODES * sizeof(int));
    int*      partials = (int*)take(256 * sizeof(int));
    int*      blockoff = (int*)take(256 * sizeof(int));
    int*      srclist  = (int*)take(((size_t)NTOT + 16) * sizeof(int));
    float*    x16      = (float*)take((size_t)NNODES * 16 * sizeof(float));
    float*    asrc4    = (float*)take((size_t)NNODES * 4 * sizeof(float));
    float*    adst4    = (float*)take((size_t)NNODES * 4 * sizeof(float));
    __half*   out1     = (__half*)take((size_t)NNODES * 256 * sizeof(__half));
    _Float16* W2T      = (_Float16*)take(64 * 256 * sizeof(_Float16));
    __half*   h2       = (__half*)take((size_t)NNODES * 64 * sizeof(__half));
    float*    as2      = (float*)take((size_t)NNODES * sizeof(float));
    float*    ad2      = (float*)take((size_t)NNODES * sizeof(float));
    float*    out2     = (float*)take((size_t)NNODES * 64 * sizeof(float));

    const int* srcs = ei;
    const int* dsts = ei + NEDGES;

    hipMemsetAsync(d_out, 0, 64 * sizeof(float), stream);

    setup_kernel<<<NB_NODE, 256, 0, stream>>>(x, W1, att_src1, att_dst1, W2,
                                              deg, x16, asrc4, adst4, W2T);
    hist_kernel<<<(NEDGES + 255) / 256, 256, 0, stream>>>(dsts, deg);
    scanA<<<NB_NODE, 256, 0, stream>>>(deg, rowstart, partials);
    scanB<<<1, 256, 0, stream>>>(partials, blockoff, rowstart, NB_NODE);
    scanC<<<NB_NODE, 256, 0, stream>>>(rowstart, blockoff, cursor);
    scatter_kernel<<<(NTOT + 255) / 256, 256, 0, stream>>>(srcs, dsts, cursor, srclist);

    layer1_aggr<<<NNODES / 4, 256, 0, stream>>>(x16, rowstart, srclist, asrc4, adst4,
                                                W1, b1, out1);

    layer2_gemm<<<(NNODES + 63) / 64, 256, 0, stream>>>(out1, W2T, h2, att_src2, att_dst2,
                                                        as2, ad2);
    layer2_aggr<<<NNODES / 4, 256, 0, stream>>>(h2, rowstart, srclist, as2, ad2, b2, out2);

    reduce_kernel<<<256, 256, 0, stream>>>(out2, out);
}